// Round 20
// baseline (389.346 us; speedup 1.0000x reference)
//
#include <hip/hip_runtime.h>
#include <math.h>

// Hardened single-rounded ops (never contracted/fused by the compiler):
#define FMUL(a,b) __fmul_rn((a),(b))
#define FADD(a,b) __fadd_rn((a),(b))
#define FSUB(a,b) __fsub_rn((a),(b))

#define BB 2048   // batch
#define DD 1024   // feature dim (K)
#define TT 32     // LIF steps
#define BM 64     // rows per block
#define BN 32     // cols per block
#define KB 32     // k per LDS slab
#define NSLAB (DD / KB)   // 32
#define HALFS (NSLAB / 2) // chunk boundary slab (k=512)

// CONFIRMED golden semantics (r16 band 7; r17/r18 passed):
//   dot = FADD( fmaf-chain(k=0..511), fmaf-chain(k=512..1023) )
//   cur = FADD(dot, bias[e]); rec: m = FSUB(FADD(FMUL(0.9f,m),cur),reset)
//
// 1-wave block (64 thr): tx=tid&7 (cols tx+8j, j<4), ty=tid>>3 (rows ty+8i, i<8).
// XOR-swizzled LDS ([row][sub^(row&7)]) -> all reads/writes bank-conflict-free.
// Dynamic-LDS pad caps residency at 3 blocks/CU -> block stream desyncs
// GEMM (LDS-bound) vs spike-write (HBM-bound) phases across blocks.
__global__ __launch_bounds__(64) void lif_fused_kernel(
    const float* __restrict__ latent,
    const float* __restrict__ W,
    const float* __restrict__ bias,
    const float* __restrict__ gainp,
    float* __restrict__ out)
{
    __shared__ float4 As4[BM * 8];   // idx = row*8 + (sub ^ (row&7))
    __shared__ float4 Ws4[BN * 8];   // idx = col*8 + (sub ^ (col&7))
    extern __shared__ char occ_pad[];  // 40 KB launch pad -> ~52KB/block -> 3/CU
    (void)occ_pad;

    const int tid = threadIdx.x;
    const int tx = tid & 7;          // col group: cols tx + 8j
    const int ty = tid >> 3;         // row group: rows ty + 8i
    const int e0 = blockIdx.x * BN;
    const int b0 = blockIdx.y * BM;

    // staging: lane loads rows/cols (r*8 + ty), k-f4 slot tx
    const float* aB = latent + (size_t)(b0 + ty) * DD + tx * 4;
    const float* wB = W      + (size_t)(e0 + ty) * DD + tx * 4;

    float4 ar[8], wr[4];
#pragma unroll
    for (int r = 0; r < 8; ++r) ar[r] = *(const float4*)(aB + (size_t)r * 8 * DD);
#pragma unroll
    for (int r = 0; r < 4; ++r) wr[r] = *(const float4*)(wB + (size_t)r * 8 * DD);

    float acc[8][4], tot[8][4];
#pragma unroll
    for (int i = 0; i < 8; ++i)
#pragma unroll
        for (int j = 0; j < 4; ++j) acc[i][j] = 0.0f;

    for (int s = 0; s < NSLAB; ++s) {
        // write staged slab to LDS (swizzled; dense conflict-free)
#pragma unroll
        for (int r = 0; r < 8; ++r) {
            const int row = r * 8 + ty;
            As4[row * 8 + (tx ^ ty)] = ar[r];
        }
#pragma unroll
        for (int r = 0; r < 4; ++r) {
            const int col = r * 8 + ty;
            Ws4[col * 8 + (tx ^ ty)] = wr[r];
        }
        // single wave: no barrier needed; compiler orders LDS write->read.

        if (s + 1 < NSLAB) {   // prefetch next slab into regs (hides HBM/L2)
            const int k0 = (s + 1) * KB;
#pragma unroll
            for (int r = 0; r < 8; ++r) ar[r] = *(const float4*)(aB + (size_t)r * 8 * DD + k0);
#pragma unroll
            for (int r = 0; r < 4; ++r) wr[r] = *(const float4*)(wB + (size_t)r * 8 * DD + k0);
        }

        if (s == HALFS) {      // chunk boundary k=512: save chunk1, restart chain
#pragma unroll
            for (int i = 0; i < 8; ++i)
#pragma unroll
                for (int j = 0; j < 4; ++j) { tot[i][j] = acc[i][j]; acc[i][j] = 0.0f; }
        }

#pragma unroll
        for (int sub = 0; sub < 8; ++sub) {
            float4 a4[8], w4[4];
#pragma unroll
            for (int i = 0; i < 8; ++i)
                a4[i] = As4[(i * 8 + ty) * 8 + (sub ^ ty)];   // 8 addrs, 8 quads: free
#pragma unroll
            for (int j = 0; j < 4; ++j)
                w4[j] = Ws4[(j * 8 + tx) * 8 + (sub ^ tx)];   // 8 addrs, 8 quads: free
#pragma unroll
            for (int j = 0; j < 4; ++j)
#pragma unroll
                for (int i = 0; i < 8; ++i) {
                    float a = acc[i][j];
                    a = fmaf(a4[i].x, w4[j].x, a);   // strict ascending k
                    a = fmaf(a4[i].y, w4[j].y, a);
                    a = fmaf(a4[i].z, w4[j].z, a);
                    a = fmaf(a4[i].w, w4[j].w, a);
                    acc[i][j] = a;
                }
        }
    }

    // cur = FADD(FADD(chunk1, chunk2), bias)  (reuse tot as cur)
    float bv[4];
#pragma unroll
    for (int j = 0; j < 4; ++j) bv[j] = bias[e0 + j * 8 + tx];
#pragma unroll
    for (int i = 0; i < 8; ++i)
#pragma unroll
        for (int j = 0; j < 4; ++j)
            tot[i][j] = FADD(FADD(tot[i][j], acc[i][j]), bv[j]);

    // hardened f32 LIF recurrence
    float mem[8][4];
    int cnt[8][4];
#pragma unroll
    for (int i = 0; i < 8; ++i)
#pragma unroll
        for (int j = 0; j < 4; ++j) { mem[i][j] = 0.0f; cnt[i][j] = 0; }

    float* spk = out + (size_t)BB * DD;
    for (int t = 0; t < TT; ++t) {
#pragma unroll
        for (int i = 0; i < 8; ++i) {
            const size_t rbase = ((size_t)(b0 + i * 8 + ty) * TT + t) * DD + e0;
#pragma unroll
            for (int j = 0; j < 4; ++j) {
                float m = mem[i][j];
                float r = (m > 1.0f) ? 1.0f : 0.0f;
                m = FSUB(FADD(FMUL(0.9f, m), tot[i][j]), r);
                mem[i][j] = m;
                int f = (m > 1.0f) ? 1 : 0;
                cnt[i][j] += f;
                spk[rbase + j * 8 + tx] = (float)f;
            }
        }
    }

    // scale = 0.4*sigmoid(gain); updated = relu(latent + scale*mean_t(spikes))
    const float g = gainp[0];
    const float scale = 0.4f * (1.0f / (1.0f + expf(-g)));
#pragma unroll
    for (int i = 0; i < 8; ++i) {
        const size_t rbase = (size_t)(b0 + i * 8 + ty) * DD + e0;
#pragma unroll
        for (int j = 0; j < 4; ++j) {
            float lv = latent[rbase + j * 8 + tx];
            float mean = (float)cnt[i][j] * 0.03125f;   // exact (pow2)
            float v = FADD(lv, FMUL(scale, mean));
            out[rbase + j * 8 + tx] = v > 0.0f ? v : 0.0f;
        }
    }

    if (blockIdx.x == 0 && blockIdx.y == 0 && tid == 0)
        out[(size_t)BB * DD + (size_t)BB * TT * DD] = scale;
}

extern "C" void kernel_launch(void* const* d_in, const int* in_sizes, int n_in,
                              void* d_out, int out_size, void* d_ws, size_t ws_size,
                              hipStream_t stream) {
    (void)in_sizes; (void)n_in; (void)d_ws; (void)ws_size; (void)out_size;
    const float* latent = (const float*)d_in[0];
    const float* W      = (const float*)d_in[1];
    const float* bias   = (const float*)d_in[2];
    const float* gain   = (const float*)d_in[3];
    float* out = (float*)d_out;

    dim3 grid(DD / BN, BB / BM);  // (32, 32) = 1024 blocks
    dim3 block(64);               // 1 wave
    // 40 KB dynamic pad -> ~52 KB/block -> 3 blocks/CU -> streaming desync
    lif_fused_kernel<<<grid, block, 40960, stream>>>(latent, W, bias, gain, out);
}

// Round 21
// 253.980 us; speedup vs baseline: 1.5330x; 1.5330x over previous
//
#include <hip/hip_runtime.h>
#include <math.h>

// Hardened single-rounded ops (never contracted/fused by the compiler):
#define FMUL(a,b) __fmul_rn((a),(b))
#define FADD(a,b) __fadd_rn((a),(b))
#define FSUB(a,b) __fsub_rn((a),(b))

#define BB 2048   // batch
#define DD 1024   // feature dim (K)
#define TT 32     // LIF steps
#define TS 64     // tile: 64 rows x 64 cols
#define KB 32     // k per LDS slab
#define NSLAB (DD / KB)   // 32
#define HALFS (NSLAB / 2) // chunk boundary slab (k=512)

// CONFIRMED golden semantics (r16 band 7; r17/r18/r19/r20 passed):
//   dot = FADD( fmaf-chain(k=0..511), fmaf-chain(k=512..1023) )
//   cur = FADD(dot, bias[e]); rec: m = FSUB(FADD(FMUL(0.9f,m),cur),reset)
//
// r21 structure: 128-thread (2-wave) block, 64x64 tile, Mt=8 x Nt=4 per thread
// (12 ds_read_b128 per 8-sub group vs r18's 8-per-4x4 => 2.7x fewer LDS instrs
// per FMA). LDS padded to ~90KB => 1 block/CU resident; grid 512 => each CU
// runs 2 blocks sequentially; gen-1 store drain overlaps gen-2 GEMM.
__global__ __launch_bounds__(128) void lif_fused_kernel(
    const float* __restrict__ latent,
    const float* __restrict__ W,
    const float* __restrict__ bias,
    const float* __restrict__ gainp,
    float* __restrict__ out)
{
    __shared__ float4 As4[2][KB / 4][TS];   // [buf][sub][row] 16 KB
    __shared__ float4 Ws4[2][KB / 4][TS];   // [buf][sub][col] 16 KB
    extern __shared__ char occ_pad[];       // +56 KB dynamic -> ~90KB/block -> 1/CU
    (void)occ_pad;

    const int tid = threadIdx.x;    // 0..127
    const int tx = tid & 15;        // col group: cols tx*4+j (float4 stores)
    const int ty = tid >> 4;        // 0..7: rows ty*8+i
    const int e0 = blockIdx.x * TS;
    const int b0 = blockIdx.y * TS;

    // staging: lane covers row lrow, wave h covers f4 slots h*4..h*4+3 (k half)
    const int lrow = tid & 63;
    const int half = tid >> 6;      // wave id 0/1
    const float* aB = latent + (size_t)(b0 + lrow) * DD + half * 16;
    const float* wB = W      + (size_t)(e0 + lrow) * DD + half * 16;

    float4 apf[4], wpf[4];
#pragma unroll
    for (int c = 0; c < 4; ++c) {
        apf[c] = *(const float4*)(aB + c * 4);
        wpf[c] = *(const float4*)(wB + c * 4);
    }

    float acc[8][4], tot[8][4];
#pragma unroll
    for (int i = 0; i < 8; ++i)
#pragma unroll
        for (int j = 0; j < 4; ++j) acc[i][j] = 0.0f;

    int p = 0;
    for (int s = 0; s < NSLAB; ++s) {
#pragma unroll
        for (int c = 0; c < 4; ++c) {
            As4[p][half * 4 + c][lrow] = apf[c];
            Ws4[p][half * 4 + c][lrow] = wpf[c];
        }
        __syncthreads();

        if (s + 1 < NSLAB) {        // prefetch next slab into regs
            const int k0 = (s + 1) * KB;
#pragma unroll
            for (int c = 0; c < 4; ++c) {
                apf[c] = *(const float4*)(aB + k0 + c * 4);
                wpf[c] = *(const float4*)(wB + k0 + c * 4);
            }
        }

        if (s == HALFS) {           // chunk boundary k=512: save S1, restart chain
#pragma unroll
            for (int i = 0; i < 8; ++i)
#pragma unroll
                for (int j = 0; j < 4; ++j) { tot[i][j] = acc[i][j]; acc[i][j] = 0.0f; }
        }

#pragma unroll
        for (int sub = 0; sub < KB / 4; ++sub) {
            float4 a4[8], w4[4];
#pragma unroll
            for (int i = 0; i < 8; ++i) a4[i] = As4[p][sub][ty * 8 + i];  // broadcast
#pragma unroll
            for (int j = 0; j < 4; ++j) w4[j] = Ws4[p][sub][tx * 4 + j];  // 2-way free
#pragma unroll
            for (int j = 0; j < 4; ++j)
#pragma unroll
                for (int i = 0; i < 8; ++i) {
                    float a = acc[i][j];
                    a = fmaf(a4[i].x, w4[j].x, a);   // strict ascending k
                    a = fmaf(a4[i].y, w4[j].y, a);
                    a = fmaf(a4[i].z, w4[j].z, a);
                    a = fmaf(a4[i].w, w4[j].w, a);
                    acc[i][j] = a;
                }
        }
        p ^= 1;
    }

    // cur = FADD(FADD(S1, S2), bias)   (reuse tot as cur)
    float4 bv = *(const float4*)&bias[e0 + tx * 4];
#pragma unroll
    for (int i = 0; i < 8; ++i) {
        tot[i][0] = FADD(FADD(tot[i][0], acc[i][0]), bv.x);
        tot[i][1] = FADD(FADD(tot[i][1], acc[i][1]), bv.y);
        tot[i][2] = FADD(FADD(tot[i][2], acc[i][2]), bv.z);
        tot[i][3] = FADD(FADD(tot[i][3], acc[i][3]), bv.w);
    }

    // hardened f32 LIF recurrence
    float mem[8][4];
    int cnt[8][4];
#pragma unroll
    for (int i = 0; i < 8; ++i)
#pragma unroll
        for (int j = 0; j < 4; ++j) { mem[i][j] = 0.0f; cnt[i][j] = 0; }

    float* spk = out + (size_t)BB * DD;
    const int colf = e0 + tx * 4;

    for (int t = 0; t < TT; ++t) {
#pragma unroll
        for (int i = 0; i < 8; ++i) {
            const int row = b0 + ty * 8 + i;
            float4 s;
#pragma unroll
            for (int j = 0; j < 4; ++j) {
                float m = mem[i][j];
                float r = (m > 1.0f) ? 1.0f : 0.0f;
                m = FSUB(FADD(FMUL(0.9f, m), tot[i][j]), r);
                mem[i][j] = m;
                int f = (m > 1.0f) ? 1 : 0;
                cnt[i][j] += f;
                ((float*)&s)[j] = (float)f;
            }
            *(float4*)&spk[((size_t)row * TT + t) * DD + colf] = s;
        }
    }

    // scale = 0.4*sigmoid(gain); updated = relu(latent + scale*mean_t(spikes))
    const float g = gainp[0];
    const float scale = 0.4f * (1.0f / (1.0f + expf(-g)));
#pragma unroll
    for (int i = 0; i < 8; ++i) {
        const int row = b0 + ty * 8 + i;
        float4 lv = *(const float4*)&latent[(size_t)row * DD + colf];
        float4 u;
#pragma unroll
        for (int j = 0; j < 4; ++j) {
            float mean = (float)cnt[i][j] * 0.03125f;   // exact (pow2)
            float v = FADD(((const float*)&lv)[j], FMUL(scale, mean));
            ((float*)&u)[j] = v > 0.0f ? v : 0.0f;
        }
        *(float4*)&out[(size_t)row * DD + colf] = u;
    }

    if (blockIdx.x == 0 && blockIdx.y == 0 && tid == 0)
        out[(size_t)BB * DD + (size_t)BB * TT * DD] = scale;
}

extern "C" void kernel_launch(void* const* d_in, const int* in_sizes, int n_in,
                              void* d_out, int out_size, void* d_ws, size_t ws_size,
                              hipStream_t stream) {
    (void)in_sizes; (void)n_in; (void)d_ws; (void)ws_size; (void)out_size;
    const float* latent = (const float*)d_in[0];
    const float* W      = (const float*)d_in[1];
    const float* bias   = (const float*)d_in[2];
    const float* gain   = (const float*)d_in[3];
    float* out = (float*)d_out;

    dim3 grid(DD / TS, BB / TS);  // (16, 32) = 512 blocks -> 2 generations/CU
    dim3 block(128);              // 2 waves
    // static 32 KB + 56 KB dynamic pad = ~90 KB/block -> exactly 1 block/CU
    lif_fused_kernel<<<grid, block, 57344, stream>>>(latent, W, bias, gain, out);
}

// Round 22
// 178.163 us; speedup vs baseline: 2.1853x; 1.4255x over previous
//
#include <hip/hip_runtime.h>
#include <math.h>

// Hardened single-rounded ops (never contracted/fused by the compiler):
#define FMUL(a,b) __fmul_rn((a),(b))
#define FADD(a,b) __fadd_rn((a),(b))
#define FSUB(a,b) __fsub_rn((a),(b))

#define BB 2048   // batch
#define DD 1024   // feature dim (K)
#define TT 32     // LIF steps
#define TS 64     // tile: 64 rows x 64 cols
#define KB 32     // k per LDS slab
#define NSLAB (DD / KB)   // 32
#define HALFS (NSLAB / 2) // chunk boundary slab (k=512)

// CONFIRMED golden semantics (r16 band 7; r17-r21 all passed bit-exact):
//   dot = FADD( fmaf-chain(k=0..511), fmaf-chain(k=512..1023) )
//   cur = FADD(dot, bias[e]); rec: m = FSUB(FADD(FMUL(0.9f,m),cur),reset)
//
// r22: 128-thr (2-wave) block, 64x64 tile, Mt=8 x Nt=4/thread. No occupancy
// pad (32KB LDS -> 2 blocks/CU resident from grid 512). Blocks flat>=256
// sleep ~30us at entry: block i and i+256 share a CU (XCD round-robin), so
// per CU: A GEMMs at full LDS rate, then A's spike-write drain overlaps B's
// GEMM. Phase stagger = cross-resource overlap without arithmetic change.
__global__ __launch_bounds__(128) void lif_fused_kernel(
    const float* __restrict__ latent,
    const float* __restrict__ W,
    const float* __restrict__ bias,
    const float* __restrict__ gainp,
    float* __restrict__ out)
{
    __shared__ float4 As4[2][KB / 4][TS];   // [buf][sub][row] 16 KB
    __shared__ float4 Ws4[2][KB / 4][TS];   // [buf][sub][col] 16 KB

    const int flatb = blockIdx.y * gridDim.x + blockIdx.x;
    if (flatb >= 256) {
        // ~30us stagger (9 x 8128 cyc at 2.4GHz); generation-2 blocks wait
        // while their CU-partner runs its GEMM phase at full LDS throughput.
#pragma unroll
        for (int z = 0; z < 9; ++z) __builtin_amdgcn_s_sleep(127);
    }

    const int tid = threadIdx.x;    // 0..127
    const int tx = tid & 15;        // col group: cols tx*4+j
    const int ty = tid >> 4;        // 0..7: rows ty*8+i
    const int e0 = blockIdx.x * TS;
    const int b0 = blockIdx.y * TS;

    // staging: lane covers row lrow, wave half covers f4 slots half*4..+3
    const int lrow = tid & 63;
    const int half = tid >> 6;      // wave id 0/1
    const float* aB = latent + (size_t)(b0 + lrow) * DD + half * 16;
    const float* wB = W      + (size_t)(e0 + lrow) * DD + half * 16;

    float4 apf[4], wpf[4];
#pragma unroll
    for (int c = 0; c < 4; ++c) {
        apf[c] = *(const float4*)(aB + c * 4);
        wpf[c] = *(const float4*)(wB + c * 4);
    }

    float acc[8][4], tot[8][4];
#pragma unroll
    for (int i = 0; i < 8; ++i)
#pragma unroll
        for (int j = 0; j < 4; ++j) acc[i][j] = 0.0f;

    int p = 0;
    for (int s = 0; s < NSLAB; ++s) {
#pragma unroll
        for (int c = 0; c < 4; ++c) {
            As4[p][half * 4 + c][lrow] = apf[c];
            Ws4[p][half * 4 + c][lrow] = wpf[c];
        }
        __syncthreads();

        if (s + 1 < NSLAB) {        // prefetch next slab into regs
            const int k0 = (s + 1) * KB;
#pragma unroll
            for (int c = 0; c < 4; ++c) {
                apf[c] = *(const float4*)(aB + k0 + c * 4);
                wpf[c] = *(const float4*)(wB + k0 + c * 4);
            }
        }

        if (s == HALFS) {           // chunk boundary k=512: save S1, restart chain
#pragma unroll
            for (int i = 0; i < 8; ++i)
#pragma unroll
                for (int j = 0; j < 4; ++j) { tot[i][j] = acc[i][j]; acc[i][j] = 0.0f; }
        }

#pragma unroll
        for (int sub = 0; sub < KB / 4; ++sub) {
            float4 a4[8], w4[4];
#pragma unroll
            for (int i = 0; i < 8; ++i) a4[i] = As4[p][sub][ty * 8 + i];  // broadcast
#pragma unroll
            for (int j = 0; j < 4; ++j) w4[j] = Ws4[p][sub][tx * 4 + j];  // 2-way free
#pragma unroll
            for (int j = 0; j < 4; ++j)
#pragma unroll
                for (int i = 0; i < 8; ++i) {
                    float a = acc[i][j];
                    a = fmaf(a4[i].x, w4[j].x, a);   // strict ascending k
                    a = fmaf(a4[i].y, w4[j].y, a);
                    a = fmaf(a4[i].z, w4[j].z, a);
                    a = fmaf(a4[i].w, w4[j].w, a);
                    acc[i][j] = a;
                }
        }
        p ^= 1;
    }

    // cur = FADD(FADD(S1, S2), bias)   (reuse tot as cur)
    float4 bv = *(const float4*)&bias[e0 + tx * 4];
#pragma unroll
    for (int i = 0; i < 8; ++i) {
        tot[i][0] = FADD(FADD(tot[i][0], acc[i][0]), bv.x);
        tot[i][1] = FADD(FADD(tot[i][1], acc[i][1]), bv.y);
        tot[i][2] = FADD(FADD(tot[i][2], acc[i][2]), bv.z);
        tot[i][3] = FADD(FADD(tot[i][3], acc[i][3]), bv.w);
    }

    // hardened f32 LIF recurrence
    float mem[8][4];
    int cnt[8][4];
#pragma unroll
    for (int i = 0; i < 8; ++i)
#pragma unroll
        for (int j = 0; j < 4; ++j) { mem[i][j] = 0.0f; cnt[i][j] = 0; }

    float* spk = out + (size_t)BB * DD;
    const int colf = e0 + tx * 4;

    for (int t = 0; t < TT; ++t) {
#pragma unroll
        for (int i = 0; i < 8; ++i) {
            const int row = b0 + ty * 8 + i;
            float4 s;
#pragma unroll
            for (int j = 0; j < 4; ++j) {
                float m = mem[i][j];
                float r = (m > 1.0f) ? 1.0f : 0.0f;
                m = FSUB(FADD(FMUL(0.9f, m), tot[i][j]), r);
                mem[i][j] = m;
                int f = (m > 1.0f) ? 1 : 0;
                cnt[i][j] += f;
                ((float*)&s)[j] = (float)f;
            }
            *(float4*)&spk[((size_t)row * TT + t) * DD + colf] = s;
        }
    }

    // scale = 0.4*sigmoid(gain); updated = relu(latent + scale*mean_t(spikes))
    const float g = gainp[0];
    const float scale = 0.4f * (1.0f / (1.0f + expf(-g)));
#pragma unroll
    for (int i = 0; i < 8; ++i) {
        const int row = b0 + ty * 8 + i;
        float4 lv = *(const float4*)&latent[(size_t)row * DD + colf];
        float4 u;
#pragma unroll
        for (int j = 0; j < 4; ++j) {
            float mean = (float)cnt[i][j] * 0.03125f;   // exact (pow2)
            float v = FADD(((const float*)&lv)[j], FMUL(scale, mean));
            ((float*)&u)[j] = v > 0.0f ? v : 0.0f;
        }
        *(float4*)&out[(size_t)row * DD + colf] = u;
    }

    if (blockIdx.x == 0 && blockIdx.y == 0 && tid == 0)
        out[(size_t)BB * DD + (size_t)BB * TT * DD] = scale;
}

extern "C" void kernel_launch(void* const* d_in, const int* in_sizes, int n_in,
                              void* d_out, int out_size, void* d_ws, size_t ws_size,
                              hipStream_t stream) {
    (void)in_sizes; (void)n_in; (void)d_ws; (void)ws_size; (void)out_size;
    const float* latent = (const float*)d_in[0];
    const float* W      = (const float*)d_in[1];
    const float* bias   = (const float*)d_in[2];
    const float* gain   = (const float*)d_in[3];
    float* out = (float*)d_out;

    dim3 grid(DD / TS, BB / TS);  // (16, 32) = 512 blocks -> 2 resident/CU
    dim3 block(128);              // 2 waves
    lif_fused_kernel<<<grid, block, 0, stream>>>(latent, W, bias, gain, out);
}

// Round 23
// 132.369 us; speedup vs baseline: 2.9414x; 1.3460x over previous
//
#include <hip/hip_runtime.h>
#include <math.h>

// Hardened single-rounded ops (never contracted/fused by the compiler):
#define FMUL(a,b) __fmul_rn((a),(b))
#define FADD(a,b) __fadd_rn((a),(b))
#define FSUB(a,b) __fsub_rn((a),(b))

#define BB 2048   // batch
#define DD 1024   // feature dim (K)
#define TT 32     // LIF steps
#define TS 64     // tile: 64 rows x 64 cols
#define KB 32     // k per LDS slab
#define NSLAB (DD / KB)   // 32
#define HALFS (NSLAB / 2) // chunk boundary slab (k=512)

// CONFIRMED golden semantics (r16 band 7; r17-r22 all passed bit-exact):
//   dot = FADD( fmaf-chain(k=0..511), fmaf-chain(k=512..1023) )
//   cur = FADD(dot, bias[e]); rec: m = FSUB(FADD(FMUL(0.9f,m),cur),reset)
//
// r23 = r18 structure (best: 125us) with ONE change: A-operands read directly
// from global (L1-broadcast: 16 tx-lanes share each address, block re-reads
// each line 16x) instead of LDS. Halves LDS-pipe instructions (W only);
// A rides the separate VMEM port and overlaps LDS + VALU + write-drain.
__global__ __launch_bounds__(256) void lif_fused_kernel(
    const float* __restrict__ latent,
    const float* __restrict__ W,
    const float* __restrict__ bias,
    const float* __restrict__ gainp,
    float* __restrict__ out)
{
    __shared__ float4 Ws4[2][KB / 4][TS];   // [buf][sub][col] 16 KB total

    const int tid = threadIdx.x;
    const int tx = tid & 15;        // col group: cols tx*4+j
    const int ty = tid >> 4;        // row group: rows ty*4+i
    const int e0 = blockIdx.x * TS;
    const int b0 = blockIdx.y * TS;

    // W staging: thread loads 2 float4 per slab (64 cols x 32 k)
    const int lrow = tid >> 2;      // 0..63 (W row = output col)
    const int lf4  = tid & 3;
    const float* wptr = W + (size_t)(e0 + lrow) * DD + lf4 * 4;

    // A row pointers (4 rows per thread), read straight from global/L1
    const float* aR0 = latent + (size_t)(b0 + ty * 4 + 0) * DD;
    const float* aR1 = latent + (size_t)(b0 + ty * 4 + 1) * DD;
    const float* aR2 = latent + (size_t)(b0 + ty * 4 + 2) * DD;
    const float* aR3 = latent + (size_t)(b0 + ty * 4 + 3) * DD;

    float4 w0 = *(const float4*)(wptr);
    float4 w1 = *(const float4*)(wptr + 16);

    float acc[4][4], tot[4][4];
#pragma unroll
    for (int i = 0; i < 4; ++i)
#pragma unroll
        for (int j = 0; j < 4; ++j) acc[i][j] = 0.0f;

    int p = 0;
    for (int s = 0; s < NSLAB; ++s) {
        Ws4[p][lf4    ][lrow] = w0;
        Ws4[p][lf4 + 4][lrow] = w1;
        __syncthreads();

        if (s + 1 < NSLAB) {        // prefetch next W slab into regs
            const int k0 = (s + 1) * KB;
            w0 = *(const float4*)(wptr + k0);
            w1 = *(const float4*)(wptr + k0 + 16);
        }

        if (s == HALFS) {           // chunk boundary k=512: save S1, restart chain
#pragma unroll
            for (int i = 0; i < 4; ++i)
#pragma unroll
                for (int j = 0; j < 4; ++j) { tot[i][j] = acc[i][j]; acc[i][j] = 0.0f; }
        }

        const int kbase = s * KB;
#pragma unroll
        for (int sub = 0; sub < KB / 4; ++sub) {
            // A from global (L1-hot, broadcast across tx lanes) - VMEM port
            float4 a4[4];
            a4[0] = *(const float4*)(aR0 + kbase + sub * 4);
            a4[1] = *(const float4*)(aR1 + kbase + sub * 4);
            a4[2] = *(const float4*)(aR2 + kbase + sub * 4);
            a4[3] = *(const float4*)(aR3 + kbase + sub * 4);
            // W from LDS (2-way conflict-free) - LDS port
            float4 w4[4];
#pragma unroll
            for (int j = 0; j < 4; ++j) w4[j] = Ws4[p][sub][tx * 4 + j];
#pragma unroll
            for (int j = 0; j < 4; ++j)
#pragma unroll
                for (int i = 0; i < 4; ++i) {
                    float a = acc[i][j];
                    a = fmaf(a4[i].x, w4[j].x, a);   // strict ascending k
                    a = fmaf(a4[i].y, w4[j].y, a);
                    a = fmaf(a4[i].z, w4[j].z, a);
                    a = fmaf(a4[i].w, w4[j].w, a);
                    acc[i][j] = a;
                }
        }
        p ^= 1;
    }

    // cur = FADD(FADD(S1, S2), bias)   (reuse tot as cur)
    float4 bv = *(const float4*)&bias[e0 + tx * 4];
#pragma unroll
    for (int i = 0; i < 4; ++i) {
        tot[i][0] = FADD(FADD(tot[i][0], acc[i][0]), bv.x);
        tot[i][1] = FADD(FADD(tot[i][1], acc[i][1]), bv.y);
        tot[i][2] = FADD(FADD(tot[i][2], acc[i][2]), bv.z);
        tot[i][3] = FADD(FADD(tot[i][3], acc[i][3]), bv.w);
    }

    // hardened f32 LIF recurrence
    float mem[4][4];
    int cnt[4][4];
#pragma unroll
    for (int i = 0; i < 4; ++i)
#pragma unroll
        for (int j = 0; j < 4; ++j) { mem[i][j] = 0.0f; cnt[i][j] = 0; }

    float* spk = out + (size_t)BB * DD;
    const int colf = e0 + tx * 4;

    for (int t = 0; t < TT; ++t) {
#pragma unroll
        for (int i = 0; i < 4; ++i) {
            const int row = b0 + ty * 4 + i;
            float4 s;
#pragma unroll
            for (int j = 0; j < 4; ++j) {
                float m = mem[i][j];
                float r = (m > 1.0f) ? 1.0f : 0.0f;
                m = FSUB(FADD(FMUL(0.9f, m), tot[i][j]), r);
                mem[i][j] = m;
                int f = (m > 1.0f) ? 1 : 0;
                cnt[i][j] += f;
                ((float*)&s)[j] = (float)f;
            }
            *(float4*)&spk[((size_t)row * TT + t) * DD + colf] = s;
        }
    }

    // scale = 0.4*sigmoid(gain); updated = relu(latent + scale*mean_t(spikes))
    const float g = gainp[0];
    const float scale = 0.4f * (1.0f / (1.0f + expf(-g)));
#pragma unroll
    for (int i = 0; i < 4; ++i) {
        const int row = b0 + ty * 4 + i;
        float4 lv = *(const float4*)&latent[(size_t)row * DD + colf];
        float4 u;
#pragma unroll
        for (int j = 0; j < 4; ++j) {
            float mean = (float)cnt[i][j] * 0.03125f;   // exact (pow2)
            float v = FADD(((const float*)&lv)[j], FMUL(scale, mean));
            ((float*)&u)[j] = v > 0.0f ? v : 0.0f;
        }
        *(float4*)&out[(size_t)row * DD + colf] = u;
    }

    if (blockIdx.x == 0 && blockIdx.y == 0 && tid == 0)
        out[(size_t)BB * DD + (size_t)BB * TT * DD] = scale;
}

extern "C" void kernel_launch(void* const* d_in, const int* in_sizes, int n_in,
                              void* d_out, int out_size, void* d_ws, size_t ws_size,
                              hipStream_t stream) {
    (void)in_sizes; (void)n_in; (void)d_ws; (void)ws_size; (void)out_size;
    const float* latent = (const float*)d_in[0];
    const float* W      = (const float*)d_in[1];
    const float* bias   = (const float*)d_in[2];
    const float* gain   = (const float*)d_in[3];
    float* out = (float*)d_out;

    dim3 grid(DD / TS, BB / TS);  // (16, 32) = 512 blocks -> 2 resident/CU
    dim3 block(256);              // 4 waves
    lif_fused_kernel<<<grid, block, 0, stream>>>(latent, W, bias, gain, out);
}